// Round 4
// baseline (345.143 us; speedup 1.0000x reference)
//
#include <hip/hip_runtime.h>

// SSIM_13443247637111 — round 4: H-first fused separable SSIM.
//  - H phase (all 256 thr): raw from global (L2-cached halo overlap),
//    6 H-convolved moment fields -> LDS ring, 24 B/px written.
//  - V phase (128 thr): 4-row sliding window over ring (84 B/px read),
//    SSIM + masked accumulate in registers.
//  - Ring 6 x 42 rows x 64 cols, rotate-swizzle (quad+slot)&15: 64.5 KB,
//    2 blocks/CU, bank-group-balanced for both access patterns.
//  - Strip 64 wide x 128 tall, 32 rows/iter, grid 8x4x48 = 1536 = 3 shifts.

#define IMH 512
#define IMW 512
#define NCH 3
#define SW 64
#define SH 128
#define SSTEP 32
#define NIT (SH / SSTEP)       // 4
#define RH 42                  // ring rows
#define NBLK 1536

__device__ __forceinline__ float4 ld4(const float* p) { return *(const float4*)p; }
__device__ __forceinline__ void st4(float* p, float4 v) { *(float4*)p = v; }

// ring index: field f, row slot, logical quad qo (0..15)
__device__ __forceinline__ int hbi(int f, int slot, int qo) {
    return ((f * RH + slot) << 6) + (((qo + slot) & 15) << 2);
}

__device__ __forceinline__ void conv11(const float* W, const float* g, float* o) {
    #pragma unroll
    for (int c = 0; c < 8; ++c) {
        float s = 0.0f;
        #pragma unroll
        for (int k = 0; k < 11; ++k) s = fmaf(g[k], W[c + 3 + k], s);
        o[c] = s;
    }
}

__global__ __launch_bounds__(256, 2) void ssim_main(
    const float* __restrict__ img1, const float* __restrict__ img2,
    const float* __restrict__ match,
    float* __restrict__ wsn, float* __restrict__ wsd,
    double* __restrict__ acc, int use_partials)
{
    __shared__ __align__(16) float hb[6 * RH * 64];   // 64512 B
    __shared__ float redn[4], redd[4];

    const int tid = threadIdx.x;
    const int bc = blockIdx.z;
    const int b = bc / NCH;
    const int c = bc - b * NCH;
    const int ystart = blockIdx.y * SH;
    const int bx0 = blockIdx.x * SW;

    const float* p1 = img1 + (size_t)(b * NCH + c) * (IMH * IMW);
    const float* p2 = img2 + (size_t)(b * NCH + c) * (IMH * IMW);
    const float* pm = match + (size_t)b * (IMH * IMW);

    float g[11];
    {
        float s = 0.0f;
        #pragma unroll
        for (int i = 0; i < 11; ++i) {
            float d = (float)(i - 5);
            g[i] = expf(-(d * d) / 4.5f);
            s += g[i];
        }
        #pragma unroll
        for (int i = 0; i < 11; ++i) g[i] /= s;
    }

    float num = 0.0f, den = 0.0f;

    // ---- H phase: rows [h0, h0+hn) (strip-relative), 8 tasks per row ----
    auto phaseH = [&](int h0, int hn) {
        for (int t = tid; t < hn * 8; t += 256) {
            int r = t >> 3, cg = t & 7;
            int ra = h0 + r;                     // strip-relative row
            int gy = ystart + ra;
            int slot = (ra + 5) % RH;
            bool rok = ((unsigned)gy < IMH);
            int rowoff = (rok ? gy : 0) * IMW;
            int gxb = bx0 + 8 * cg - 8;          // global col of window[0]

            float X1[24], X2[24], XM[24];
            #pragma unroll
            for (int j = 0; j < 6; ++j) {
                int gx = gxb + 4 * j;
                if (rok && gx >= 0 && gx <= IMW - 4) {
                    float4 a = ld4(p1 + rowoff + gx);
                    float4 bb = ld4(p2 + rowoff + gx);
                    float4 m = ld4(pm + rowoff + gx);
                    X1[4*j] = a.x;  X1[4*j+1] = a.y;  X1[4*j+2] = a.z;  X1[4*j+3] = a.w;
                    X2[4*j] = bb.x; X2[4*j+1] = bb.y; X2[4*j+2] = bb.z; X2[4*j+3] = bb.w;
                    XM[4*j] = m.x;  XM[4*j+1] = m.y;  XM[4*j+2] = m.z;  XM[4*j+3] = m.w;
                } else {
                    #pragma unroll
                    for (int e = 0; e < 4; ++e) {
                        int gx2 = gx + e;
                        bool ok = rok && ((unsigned)gx2 < IMW);
                        int off = ok ? (rowoff + gx2) : 0;
                        float v1 = p1[off], v2 = p2[off], vm = pm[off];
                        X1[4*j+e] = ok ? v1 : 0.0f;
                        X2[4*j+e] = ok ? v2 : 0.0f;
                        XM[4*j+e] = ok ? vm : 0.0f;
                    }
                }
            }

            float O[8];
            auto store8 = [&](int f) {
                st4(&hb[hbi(f, slot, 2 * cg)],
                    make_float4(O[0], O[1], O[2], O[3]));
                st4(&hb[hbi(f, slot, 2 * cg + 1)],
                    make_float4(O[4], O[5], O[6], O[7]));
            };
            conv11(X1, g, O); store8(0);
            conv11(X2, g, O); store8(1);
            float P[24];
            #pragma unroll
            for (int j = 0; j < 24; ++j) P[j] = X1[j] * X2[j];
            conv11(P, g, O); store8(4);
            #pragma unroll
            for (int j = 0; j < 24; ++j) P[j] = X1[j] * X1[j];
            conv11(P, g, O); store8(2);
            #pragma unroll
            for (int j = 0; j < 24; ++j) P[j] = X2[j] * X2[j];
            conv11(P, g, O); store8(3);
            #pragma unroll
            for (int cc = 0; cc < 8; ++cc) {
                float s = 0.0f;
                #pragma unroll
                for (int k = 0; k < 11; ++k) s += XM[cc + 3 + k];
                O[cc] = s;
            }
            store8(5);
        }
    };

    // prologue: rows [-5, 5)
    phaseH(-5, 10);

    for (int i = 0; i < NIT; ++i) {
        // produce rows [32i+5, 32i+37): 32 rows x 8 = 256 tasks
        phaseH(SSTEP * i + 5, SSTEP);
        __syncthreads();   // H-writes visible

        // ---- V phase: 128 tasks, 4 output rows per thread ----
        if (tid < 128) {
            int qd = tid & 15, rg = tid >> 4;    // rg 0..7
            int ro = SSTEP * i + 4 * rg;         // first output row
            int s0 = ro % RH;                    // slot of row ro-5

            float accv[6][16];
            #pragma unroll
            for (int f = 0; f < 6; ++f)
                #pragma unroll
                for (int j = 0; j < 16; ++j) accv[f][j] = 0.0f;

            #pragma unroll
            for (int f = 0; f < 6; ++f) {
                float w[56];
                int s = s0;
                #pragma unroll
                for (int k = 0; k < 14; ++k) {
                    float4 v = ld4(&hb[hbi(f, s, qd)]);
                    w[4*k] = v.x; w[4*k+1] = v.y; w[4*k+2] = v.z; w[4*k+3] = v.w;
                    ++s; if (s == RH) s = 0;
                }
                if (f < 5) {
                    #pragma unroll
                    for (int r = 0; r < 4; ++r)
                        #pragma unroll
                        for (int k = 0; k < 11; ++k)
                            #pragma unroll
                            for (int cc = 0; cc < 4; ++cc)
                                accv[f][4*r+cc] =
                                    fmaf(g[k], w[4*(r+k)+cc], accv[f][4*r+cc]);
                } else {
                    #pragma unroll
                    for (int r = 0; r < 4; ++r)
                        #pragma unroll
                        for (int k = 0; k < 11; ++k)
                            #pragma unroll
                            for (int cc = 0; cc < 4; ++cc)
                                accv[5][4*r+cc] += w[4*(r+k)+cc];
                }
            }

            #pragma unroll
            for (int j = 0; j < 16; ++j) {
                float mu1 = accv[0][j], mu2 = accv[1][j];
                float mu1s = mu1 * mu1, mu2s = mu2 * mu2, mu12 = mu1 * mu2;
                float s11 = accv[2][j] - mu1s;
                float s22 = accv[3][j] - mu2s;
                float s12 = accv[4][j] - mu12;
                float ssim = ((2.0f * mu12 + 1e-4f) * (2.0f * s12 + 9e-4f)) /
                             ((mu1s + mu2s + 1e-4f) * (s11 + s22 + 9e-4f));
                float m = fmaf(accv[5][j], (1.0f / 121.0f), 1e-7f);
                float mask = (m > 0.5f) ? (1.0f + 1e-7f) : 1e-7f;
                num = fmaf(1.0f - ssim, mask, num);
                den += mask;
            }
        }
        __syncthreads();   // V-reads done before next H overwrites
    }

    // ---- block reduction ----
    for (int off = 32; off > 0; off >>= 1) {
        num += __shfl_down(num, off);
        den += __shfl_down(den, off);
    }
    int wave = tid >> 6;
    int lane = tid & 63;
    if (lane == 0) { redn[wave] = num; redd[wave] = den; }
    __syncthreads();
    if (tid == 0) {
        float n = redn[0] + redn[1] + redn[2] + redn[3];
        float d = redd[0] + redd[1] + redd[2] + redd[3];
        if (use_partials) {
            int bid = (blockIdx.z * gridDim.y + blockIdx.y) * gridDim.x + blockIdx.x;
            wsn[bid] = n;
            wsd[bid] = d;
        } else {
            atomicAdd(&acc[0], (double)n);
            if (c == 0) atomicAdd(&acc[1], (double)d);
        }
    }
}

__global__ void finalize_partials(const float* __restrict__ wsn,
                                  const float* __restrict__ wsd,
                                  float* __restrict__ out) {
    __shared__ double rn[4], rd[4];
    int tid = threadIdx.x;
    double num = 0.0, den = 0.0;
    for (int i = tid; i < NBLK; i += 256) {
        num += (double)wsn[i];
        int z = i >> 5;            // 8x4 = 32 blocks per z
        if (z % NCH == 0) den += (double)wsd[i];
    }
    for (int off = 32; off > 0; off >>= 1) {
        num += __shfl_down(num, off);
        den += __shfl_down(den, off);
    }
    int wave = tid >> 6, lane = tid & 63;
    if (lane == 0) { rn[wave] = num; rd[wave] = den; }
    __syncthreads();
    if (tid == 0) {
        num = rn[0] + rn[1] + rn[2] + rn[3];
        den = rd[0] + rd[1] + rd[2] + rd[3];
        out[0] = (float)(num / den / 3.0);
    }
}

__global__ void init_acc(double* acc) { acc[0] = 0.0; acc[1] = 0.0; }

__global__ void finalize_atomic(const double* __restrict__ acc,
                                float* __restrict__ out) {
    out[0] = (float)(acc[0] / acc[1] / 3.0);
}

extern "C" void kernel_launch(void* const* d_in, const int* in_sizes, int n_in,
                              void* d_out, int out_size, void* d_ws, size_t ws_size,
                              hipStream_t stream) {
    const float* img1  = (const float*)d_in[0];
    const float* img2  = (const float*)d_in[1];
    const float* match = (const float*)d_in[2];
    float* out = (float*)d_out;

    dim3 grid(IMW / SW, IMH / SH, 16 * NCH);   // 8 x 4 x 48 = 1536
    dim3 block(256, 1, 1);

    int use_partials = (ws_size >= (size_t)(2 * NBLK * sizeof(float))) ? 1 : 0;
    if (use_partials) {
        float* wsn = (float*)d_ws;
        float* wsd = wsn + NBLK;
        ssim_main<<<grid, block, 0, stream>>>(img1, img2, match, wsn, wsd,
                                              (double*)nullptr, 1);
        finalize_partials<<<1, 256, 0, stream>>>(wsn, wsd, out);
    } else {
        double* acc = (double*)d_ws;
        init_acc<<<1, 1, 0, stream>>>(acc);
        ssim_main<<<grid, block, 0, stream>>>(img1, img2, match,
                                              (float*)nullptr, (float*)nullptr,
                                              acc, 0);
        finalize_atomic<<<1, 1, 0, stream>>>(acc, out);
    }
}

// Round 5
// 312.364 us; speedup vs baseline: 1.1049x; 1.1049x over previous
//
#include <hip/hip_runtime.h>

// SSIM_13443247637111 — round 5: H-first, spill-free, full-wave phases.
//  - H phase (256 tasks): raw from global, 6 H-conv fields -> LDS ring.
//  - V phase (256 tasks, 2 rows x 4 cols each): streamed per-field
//    accumulation (no big register windows), SSIM in registers.
//  - Ring 6 x 42 x 64 f32, rotate-swizzle (quad+slot)&15, 64.5 KB,
//    2 blocks/CU. No launch_bounds VGPR cap (round-4 spill lesson).

#define IMH 512
#define IMW 512
#define NCH 3
#define SW 64
#define SH 128
#define SSTEP 32
#define NIT (SH / SSTEP)       // 4
#define RH 42                  // ring rows
#define NBLK 1536

__device__ __forceinline__ float4 ld4(const float* p) { return *(const float4*)p; }
__device__ __forceinline__ void st4(float* p, float4 v) { *(float4*)p = v; }

// ring index: field f, row slot, logical quad qo (0..15)
__device__ __forceinline__ int hbi(int f, int slot, int qo) {
    return ((f * RH + slot) << 6) + (((qo + slot) & 15) << 2);
}

__global__ __launch_bounds__(256) void ssim_main(
    const float* __restrict__ img1, const float* __restrict__ img2,
    const float* __restrict__ match,
    float* __restrict__ wsn, float* __restrict__ wsd,
    double* __restrict__ acc, int use_partials)
{
    __shared__ __align__(16) float hb[6 * RH * 64];   // 64512 B
    __shared__ float redn[4], redd[4];

    const int tid = threadIdx.x;
    const int bc = blockIdx.z;
    const int b = bc / NCH;
    const int c = bc - b * NCH;
    const int ystart = blockIdx.y * SH;
    const int bx0 = blockIdx.x * SW;

    const float* p1 = img1 + (size_t)(b * NCH + c) * (IMH * IMW);
    const float* p2 = img2 + (size_t)(b * NCH + c) * (IMH * IMW);
    const float* pm = match + (size_t)b * (IMH * IMW);

    float g[11];
    {
        float s = 0.0f;
        #pragma unroll
        for (int i = 0; i < 11; ++i) {
            float d = (float)(i - 5);
            g[i] = expf(-(d * d) / 4.5f);
            s += g[i];
        }
        #pragma unroll
        for (int i = 0; i < 11; ++i) g[i] /= s;
    }

    float num = 0.0f, den = 0.0f;

    // ---- H phase: rows [h0, h0+hn) strip-relative, 8 tasks/row ----
    auto phaseH = [&](int h0, int hn) {
        for (int t = tid; t < hn * 8; t += 256) {
            int r = t >> 3, cg = t & 7;
            int ra = h0 + r;
            int gy = ystart + ra;
            int slot = (ra + 5) % RH;
            bool rok = ((unsigned)gy < IMH);
            int rowoff = (rok ? gy : 0) * IMW;
            int gxb = bx0 + 8 * cg - 8;          // global col of window[0]

            float X1[24], X2[24], P[24], O[8];

            auto load24 = [&](const float* __restrict__ src, float* dst) {
                #pragma unroll
                for (int j = 0; j < 6; ++j) {
                    int gx = gxb + 4 * j;
                    if (rok && gx >= 0 && gx <= IMW - 4) {
                        float4 v = ld4(src + rowoff + gx);
                        dst[4*j] = v.x; dst[4*j+1] = v.y;
                        dst[4*j+2] = v.z; dst[4*j+3] = v.w;
                    } else {
                        #pragma unroll
                        for (int e = 0; e < 4; ++e) {
                            int gx2 = gx + e;
                            bool ok = rok && ((unsigned)gx2 < IMW);
                            float v = src[ok ? (rowoff + gx2) : 0];
                            dst[4*j+e] = ok ? v : 0.0f;
                        }
                    }
                }
            };
            auto convO = [&](const float* W) {
                #pragma unroll
                for (int cc = 0; cc < 8; ++cc) {
                    float s = 0.0f;
                    #pragma unroll
                    for (int k = 0; k < 11; ++k) s = fmaf(g[k], W[cc + 3 + k], s);
                    O[cc] = s;
                }
            };
            auto store8 = [&](int f) {
                st4(&hb[hbi(f, slot, 2 * cg)], make_float4(O[0], O[1], O[2], O[3]));
                st4(&hb[hbi(f, slot, 2 * cg + 1)], make_float4(O[4], O[5], O[6], O[7]));
            };

            load24(p1, X1);
            load24(p2, X2);
            convO(X1); store8(0);
            convO(X2); store8(1);
            #pragma unroll
            for (int j = 0; j < 24; ++j) P[j] = X1[j] * X2[j];
            convO(P); store8(4);
            #pragma unroll
            for (int j = 0; j < 24; ++j) P[j] = X1[j] * X1[j];
            convO(P); store8(2);
            #pragma unroll
            for (int j = 0; j < 24; ++j) P[j] = X2[j] * X2[j];
            convO(P); store8(3);
            load24(pm, X1);                       // reuse X1 for match
            #pragma unroll
            for (int cc = 0; cc < 8; ++cc) {
                float s = 0.0f;
                #pragma unroll
                for (int k = 0; k < 11; ++k) s += X1[cc + 3 + k];
                O[cc] = s;
            }
            store8(5);
        }
    };

    // prologue: rows [-5, 5)
    phaseH(-5, 10);

    for (int i = 0; i < NIT; ++i) {
        // produce H-field rows [32i+5, 32i+37)
        phaseH(SSTEP * i + 5, SSTEP);
        __syncthreads();   // B1: ring writes visible

        // ---- V phase: 256 tasks = 16 quads x 16 row-pairs ----
        {
            int qd = tid & 15, pj = tid >> 4;      // pj 0..15
            int r0 = SSTEP * i + 2 * pj;           // output rows r0, r0+1
            int s0 = r0 % RH;                      // slot of row r0-5

            float res[6][8];
            #pragma unroll
            for (int f = 0; f < 6; ++f) {
                float a0x = 0.f, a0y = 0.f, a0z = 0.f, a0w = 0.f;
                float a1x = 0.f, a1y = 0.f, a1z = 0.f, a1w = 0.f;
                int s = s0;
                #pragma unroll
                for (int k = 0; k < 12; ++k) {     // rows r0-5 .. r0+6
                    float4 v = ld4(&hb[hbi(f, s, qd)]);
                    if (f < 5) {
                        if (k < 11) {
                            float w = g[k];
                            a0x = fmaf(w, v.x, a0x); a0y = fmaf(w, v.y, a0y);
                            a0z = fmaf(w, v.z, a0z); a0w = fmaf(w, v.w, a0w);
                        }
                        if (k > 0) {
                            float w = g[k - 1];
                            a1x = fmaf(w, v.x, a1x); a1y = fmaf(w, v.y, a1y);
                            a1z = fmaf(w, v.z, a1z); a1w = fmaf(w, v.w, a1w);
                        }
                    } else {
                        if (k < 11) { a0x += v.x; a0y += v.y; a0z += v.z; a0w += v.w; }
                        if (k > 0)  { a1x += v.x; a1y += v.y; a1z += v.z; a1w += v.w; }
                    }
                    ++s; if (s == RH) s = 0;
                }
                res[f][0] = a0x; res[f][1] = a0y; res[f][2] = a0z; res[f][3] = a0w;
                res[f][4] = a1x; res[f][5] = a1y; res[f][6] = a1z; res[f][7] = a1w;
            }

            #pragma unroll
            for (int j = 0; j < 8; ++j) {
                float mu1 = res[0][j], mu2 = res[1][j];
                float mu1s = mu1 * mu1, mu2s = mu2 * mu2, mu12 = mu1 * mu2;
                float s11 = res[2][j] - mu1s;
                float s22 = res[3][j] - mu2s;
                float s12 = res[4][j] - mu12;
                float ssim = ((2.0f * mu12 + 1e-4f) * (2.0f * s12 + 9e-4f)) /
                             ((mu1s + mu2s + 1e-4f) * (s11 + s22 + 9e-4f));
                float m = fmaf(res[5][j], (1.0f / 121.0f), 1e-7f);
                float mask = (m > 0.5f) ? (1.0f + 1e-7f) : 1e-7f;
                num = fmaf(1.0f - ssim, mask, num);
                den += mask;
            }
        }
        __syncthreads();   // B2: V reads done before next H overwrites ring
    }

    // ---- block reduction ----
    for (int off = 32; off > 0; off >>= 1) {
        num += __shfl_down(num, off);
        den += __shfl_down(den, off);
    }
    int wave = tid >> 6;
    int lane = tid & 63;
    if (lane == 0) { redn[wave] = num; redd[wave] = den; }
    __syncthreads();
    if (tid == 0) {
        float n = redn[0] + redn[1] + redn[2] + redn[3];
        float d = redd[0] + redd[1] + redd[2] + redd[3];
        if (use_partials) {
            int bid = (blockIdx.z * gridDim.y + blockIdx.y) * gridDim.x + blockIdx.x;
            wsn[bid] = n;
            wsd[bid] = d;
        } else {
            atomicAdd(&acc[0], (double)n);
            if (c == 0) atomicAdd(&acc[1], (double)d);
        }
    }
}

__global__ void finalize_partials(const float* __restrict__ wsn,
                                  const float* __restrict__ wsd,
                                  float* __restrict__ out) {
    __shared__ double rn[4], rd[4];
    int tid = threadIdx.x;
    double num = 0.0, den = 0.0;
    for (int i = tid; i < NBLK; i += 256) {
        num += (double)wsn[i];
        int z = i >> 5;            // 8x4 = 32 blocks per z
        if (z % NCH == 0) den += (double)wsd[i];
    }
    for (int off = 32; off > 0; off >>= 1) {
        num += __shfl_down(num, off);
        den += __shfl_down(den, off);
    }
    int wave = tid >> 6, lane = tid & 63;
    if (lane == 0) { rn[wave] = num; rd[wave] = den; }
    __syncthreads();
    if (tid == 0) {
        num = rn[0] + rn[1] + rn[2] + rn[3];
        den = rd[0] + rd[1] + rd[2] + rd[3];
        out[0] = (float)(num / den / 3.0);
    }
}

__global__ void init_acc(double* acc) { acc[0] = 0.0; acc[1] = 0.0; }

__global__ void finalize_atomic(const double* __restrict__ acc,
                                float* __restrict__ out) {
    out[0] = (float)(acc[0] / acc[1] / 3.0);
}

extern "C" void kernel_launch(void* const* d_in, const int* in_sizes, int n_in,
                              void* d_out, int out_size, void* d_ws, size_t ws_size,
                              hipStream_t stream) {
    const float* img1  = (const float*)d_in[0];
    const float* img2  = (const float*)d_in[1];
    const float* match = (const float*)d_in[2];
    float* out = (float*)d_out;

    dim3 grid(IMW / SW, IMH / SH, 16 * NCH);   // 8 x 4 x 48 = 1536
    dim3 block(256, 1, 1);

    int use_partials = (ws_size >= (size_t)(2 * NBLK * sizeof(float))) ? 1 : 0;
    if (use_partials) {
        float* wsn = (float*)d_ws;
        float* wsd = wsn + NBLK;
        ssim_main<<<grid, block, 0, stream>>>(img1, img2, match, wsn, wsd,
                                              (double*)nullptr, 1);
        finalize_partials<<<1, 256, 0, stream>>>(wsn, wsd, out);
    } else {
        double* acc = (double*)d_ws;
        init_acc<<<1, 1, 0, stream>>>(acc);
        ssim_main<<<grid, block, 0, stream>>>(img1, img2, match,
                                              (float*)nullptr, (float*)nullptr,
                                              acc, 0);
        finalize_atomic<<<1, 1, 0, stream>>>(acc, out);
    }
}

// Round 6
// 306.555 us; speedup vs baseline: 1.1259x; 1.0189x over previous
//
#include <hip/hip_runtime.h>

// SSIM_13443247637111 — round 6: single-wave blocks, H-first ring.
//  - 64-thread (1-wave) workgroups: no cross-wave barrier coupling; wave
//    program order protects the LDS ring; barriers are ~free.
//  - Ring 6 fields x 19 rows x 64 cols f32, rotate-swizzle (quad+slot)&15:
//    29184 B -> >=4 blocks/CU resident, all independent.
//  - H phase: raw from global (L1/L2 halo), 6 H-conv fields -> ring.
//  - V phase: 64 tasks (16 quads x 4 row-pairs), 12 precomputed swizzled
//    offsets shared across 6 fields, SSIM + masked accumulate in registers.
//  - Strip 64x64, SSTEP 8, grid 8x8x48 = 3072 blocks (12/CU).

#define IMH 512
#define IMW 512
#define NCH 3
#define SW 64
#define SH 64
#define SSTEP 8
#define NIT (SH / SSTEP)       // 8
#define RING 19
#define NBLK 3072

__device__ __forceinline__ float4 ld4(const float* p) { return *(const float4*)p; }
__device__ __forceinline__ void st4(float* p, float4 v) { *(float4*)p = v; }

// LDS index: field f, row slot, logical quad qo (0..15), rotate-swizzled
__device__ __forceinline__ int hbi(int f, int slot, int qo) {
    return ((f * RING + slot) << 6) + (((qo + slot) & 15) << 2);
}

__global__ __launch_bounds__(64) void ssim_main(
    const float* __restrict__ img1, const float* __restrict__ img2,
    const float* __restrict__ match,
    float* __restrict__ wsn, float* __restrict__ wsd,
    double* __restrict__ acc, int use_partials)
{
    __shared__ __align__(16) float hb[6 * RING * 64];   // 29184 B

    const int tid = threadIdx.x;              // 0..63
    const int bc = blockIdx.z;
    const int b = bc / NCH;
    const int c = bc - b * NCH;
    const int ystart = blockIdx.y * SH;
    const int bx0 = blockIdx.x * SW;

    const float* p1 = img1 + (size_t)(b * NCH + c) * (IMH * IMW);
    const float* p2 = img2 + (size_t)(b * NCH + c) * (IMH * IMW);
    const float* pm = match + (size_t)b * (IMH * IMW);

    float g[11];
    {
        float s = 0.0f;
        #pragma unroll
        for (int i = 0; i < 11; ++i) {
            float d = (float)(i - 5);
            g[i] = expf(-(d * d) / 4.5f);
            s += g[i];
        }
        #pragma unroll
        for (int i = 0; i < 11; ++i) g[i] /= s;
    }

    float num = 0.0f, den = 0.0f;

    // ---- H phase: rows [h0, h0+hn) strip-relative, 8 tasks/row ----
    auto phaseH = [&](int h0, int hn) {
        for (int t = tid; t < hn * 8; t += 64) {
            int r = t >> 3, cg = t & 7;
            int ra = h0 + r;
            int gy = ystart + ra;
            int slot = (ra + 5) % RING;
            bool rok = ((unsigned)gy < IMH);
            int rowoff = (rok ? gy : 0) * IMW;
            int gxb = bx0 + 8 * cg - 8;          // global col of window[0]

            float X1[24], X2[24], P[24], O[8];

            auto load24 = [&](const float* __restrict__ src, float* dst) {
                #pragma unroll
                for (int j = 0; j < 6; ++j) {
                    int gx = gxb + 4 * j;
                    if (rok && gx >= 0 && gx <= IMW - 4) {
                        float4 v = ld4(src + rowoff + gx);
                        dst[4*j] = v.x; dst[4*j+1] = v.y;
                        dst[4*j+2] = v.z; dst[4*j+3] = v.w;
                    } else {
                        #pragma unroll
                        for (int e = 0; e < 4; ++e) {
                            int gx2 = gx + e;
                            bool ok = rok && ((unsigned)gx2 < IMW);
                            float v = src[ok ? (rowoff + gx2) : 0];
                            dst[4*j+e] = ok ? v : 0.0f;
                        }
                    }
                }
            };
            auto convO = [&](const float* W) {
                #pragma unroll
                for (int cc = 0; cc < 8; ++cc) {
                    float s = 0.0f;
                    #pragma unroll
                    for (int k = 0; k < 11; ++k) s = fmaf(g[k], W[cc + 3 + k], s);
                    O[cc] = s;
                }
            };
            auto store8 = [&](int f) {
                st4(&hb[hbi(f, slot, 2 * cg)], make_float4(O[0], O[1], O[2], O[3]));
                st4(&hb[hbi(f, slot, 2 * cg + 1)], make_float4(O[4], O[5], O[6], O[7]));
            };

            load24(p1, X1);
            load24(p2, X2);
            convO(X1); store8(0);
            convO(X2); store8(1);
            #pragma unroll
            for (int j = 0; j < 24; ++j) P[j] = X1[j] * X2[j];
            convO(P); store8(4);
            #pragma unroll
            for (int j = 0; j < 24; ++j) P[j] = X1[j] * X1[j];
            convO(P); store8(2);
            #pragma unroll
            for (int j = 0; j < 24; ++j) P[j] = X2[j] * X2[j];
            convO(P); store8(3);
            load24(pm, X1);                       // reuse X1 for match
            #pragma unroll
            for (int cc = 0; cc < 8; ++cc) {
                float s = 0.0f;
                #pragma unroll
                for (int k = 0; k < 11; ++k) s += X1[cc + 3 + k];
                O[cc] = s;
            }
            store8(5);
        }
    };

    // prologue: rows [-5, 5)
    phaseH(-5, 10);

    for (int i = 0; i < NIT; ++i) {
        // produce H-field rows [8i+5, 8i+13)
        phaseH(SSTEP * i + 5, SSTEP);
        __syncthreads();   // fence (1 wave: near-free)

        // ---- V phase: 64 tasks = 16 quads x 4 row-pairs ----
        {
            int qd = tid & 15, pj = tid >> 4;      // pj 0..3
            int r0 = SSTEP * i + 2 * pj;           // output rows r0, r0+1
            int s0 = r0 % RING;                    // slot of row r0-5

            int off[12];
            {
                int s = s0;
                #pragma unroll
                for (int k = 0; k < 12; ++k) {
                    off[k] = (s << 6) + (((qd + s) & 15) << 2);
                    ++s; if (s == RING) s = 0;
                }
            }

            float res[6][8];
            #pragma unroll
            for (int f = 0; f < 6; ++f) {
                const float* base = hb + f * (RING * 64);
                float a0x = 0.f, a0y = 0.f, a0z = 0.f, a0w = 0.f;
                float a1x = 0.f, a1y = 0.f, a1z = 0.f, a1w = 0.f;
                #pragma unroll
                for (int k = 0; k < 12; ++k) {     // rows r0-5 .. r0+6
                    float4 v = ld4(base + off[k]);
                    if (f < 5) {
                        if (k < 11) {
                            float w = g[k];
                            a0x = fmaf(w, v.x, a0x); a0y = fmaf(w, v.y, a0y);
                            a0z = fmaf(w, v.z, a0z); a0w = fmaf(w, v.w, a0w);
                        }
                        if (k > 0) {
                            float w = g[k - 1];
                            a1x = fmaf(w, v.x, a1x); a1y = fmaf(w, v.y, a1y);
                            a1z = fmaf(w, v.z, a1z); a1w = fmaf(w, v.w, a1w);
                        }
                    } else {
                        if (k < 11) { a0x += v.x; a0y += v.y; a0z += v.z; a0w += v.w; }
                        if (k > 0)  { a1x += v.x; a1y += v.y; a1z += v.z; a1w += v.w; }
                    }
                }
                res[f][0] = a0x; res[f][1] = a0y; res[f][2] = a0z; res[f][3] = a0w;
                res[f][4] = a1x; res[f][5] = a1y; res[f][6] = a1z; res[f][7] = a1w;
            }

            #pragma unroll
            for (int j = 0; j < 8; ++j) {
                float mu1 = res[0][j], mu2 = res[1][j];
                float mu1s = mu1 * mu1, mu2s = mu2 * mu2, mu12 = mu1 * mu2;
                float s11 = res[2][j] - mu1s;
                float s22 = res[3][j] - mu2s;
                float s12 = res[4][j] - mu12;
                float ssim = ((2.0f * mu12 + 1e-4f) * (2.0f * s12 + 9e-4f)) /
                             ((mu1s + mu2s + 1e-4f) * (s11 + s22 + 9e-4f));
                float m = fmaf(res[5][j], (1.0f / 121.0f), 1e-7f);
                float mask = (m > 0.5f) ? (1.0f + 1e-7f) : 1e-7f;
                num = fmaf(1.0f - ssim, mask, num);
                den += mask;
            }
        }
        __syncthreads();   // fence before next H overwrites ring
    }

    // ---- wave reduction (single wave per block) ----
    for (int off = 32; off > 0; off >>= 1) {
        num += __shfl_down(num, off);
        den += __shfl_down(den, off);
    }
    if (tid == 0) {
        if (use_partials) {
            int bid = (blockIdx.z * gridDim.y + blockIdx.y) * gridDim.x + blockIdx.x;
            wsn[bid] = num;
            wsd[bid] = den;
        } else {
            atomicAdd(&acc[0], (double)num);
            if (c == 0) atomicAdd(&acc[1], (double)den);
        }
    }
}

__global__ void finalize_partials(const float* __restrict__ wsn,
                                  const float* __restrict__ wsd,
                                  float* __restrict__ out) {
    __shared__ double rn[4], rd[4];
    int tid = threadIdx.x;
    double num = 0.0, den = 0.0;
    for (int i = tid; i < NBLK; i += 256) {
        num += (double)wsn[i];
        int z = i >> 6;            // 8x8 = 64 blocks per z-slice
        if (z % NCH == 0) den += (double)wsd[i];
    }
    for (int off = 32; off > 0; off >>= 1) {
        num += __shfl_down(num, off);
        den += __shfl_down(den, off);
    }
    int wave = tid >> 6, lane = tid & 63;
    if (lane == 0) { rn[wave] = num; rd[wave] = den; }
    __syncthreads();
    if (tid == 0) {
        num = rn[0] + rn[1] + rn[2] + rn[3];
        den = rd[0] + rd[1] + rd[2] + rd[3];
        out[0] = (float)(num / den / 3.0);
    }
}

__global__ void init_acc(double* acc) { acc[0] = 0.0; acc[1] = 0.0; }

__global__ void finalize_atomic(const double* __restrict__ acc,
                                float* __restrict__ out) {
    out[0] = (float)(acc[0] / acc[1] / 3.0);
}

extern "C" void kernel_launch(void* const* d_in, const int* in_sizes, int n_in,
                              void* d_out, int out_size, void* d_ws, size_t ws_size,
                              hipStream_t stream) {
    const float* img1  = (const float*)d_in[0];
    const float* img2  = (const float*)d_in[1];
    const float* match = (const float*)d_in[2];
    float* out = (float*)d_out;

    dim3 grid(IMW / SW, IMH / SH, 16 * NCH);   // 8 x 8 x 48 = 3072
    dim3 block(64, 1, 1);

    int use_partials = (ws_size >= (size_t)(2 * NBLK * sizeof(float))) ? 1 : 0;
    if (use_partials) {
        float* wsn = (float*)d_ws;
        float* wsd = wsn + NBLK;
        ssim_main<<<grid, block, 0, stream>>>(img1, img2, match, wsn, wsd,
                                              (double*)nullptr, 1);
        finalize_partials<<<1, 256, 0, stream>>>(wsn, wsd, out);
    } else {
        double* acc = (double*)d_ws;
        init_acc<<<1, 1, 0, stream>>>(acc);
        ssim_main<<<grid, block, 0, stream>>>(img1, img2, match,
                                              (float*)nullptr, (float*)nullptr,
                                              acc, 0);
        finalize_atomic<<<1, 1, 0, stream>>>(acc, out);
    }
}